// Round 8
// baseline (189.666 us; speedup 1.0000x reference)
//
#include <hip/hip_runtime.h>
#include <hip/hip_bf16.h>

// ---------------------------------------------------------------------------
// Fused: GroupNorm -> QKV (1x1 conv) -> 8-head attention (n=1024,d=64)
//        -> proj (1x1 conv) + bias + residual(xn)
// b=8, c=512, n=1024, GROUPS=8, HEADS=8, dim_head=64. bf16 MFMA, fp32 accum.
// R8: BARRIER-FREE attention — K/V fragments loaded per-lane directly from
//     global (qT/kT/vK layouts make each fragment a contiguous 16B chunk;
//     L2-resident via XCD swizzle). LDS only holds the wave-private P
//     round-trip (no __syncthreads in the whole kernel).
// ---------------------------------------------------------------------------

typedef short bf16x8 __attribute__((ext_vector_type(8)));
typedef float f32x4 __attribute__((ext_vector_type(4)));
typedef unsigned short u16x4 __attribute__((ext_vector_type(4)));

#define MFMA16(a, b, c) __builtin_amdgcn_mfma_f32_16x16x32_bf16(a, b, c, 0, 0, 0)
#define EXP2(x) __builtin_amdgcn_exp2f(x)
// rotate-right by N within each 16-lane row (pure VALU DPP)
#define ROR16(v, N) __int_as_float(__builtin_amdgcn_mov_dpp(__float_as_int(v), 0x120 + (N), 0xF, 0xF, false))

__device__ __forceinline__ unsigned short f2bf(float f) {
    unsigned u = __float_as_uint(f);
    u += 0x7fffu + ((u >> 16) & 1u);   // round-to-nearest-even
    return (unsigned short)(u >> 16);
}

// pack two fp32 -> u32 of two bf16 (lo=a, hi=b), RNE via HIP intrinsic
__device__ __forceinline__ unsigned pk2(float a, float b) {
    __hip_bfloat162 h = __float22bfloat162_rn(float2{a, b});
    unsigned r;
    __builtin_memcpy(&r, &h, 4);
    return r;
}

// ---------------- K0: convert weights fp32 -> bf16 -------------------------
__global__ __launch_bounds__(256) void cvt_weights(
    const float* __restrict__ wq, const float* __restrict__ wo,
    unsigned short* __restrict__ wqb, unsigned short* __restrict__ wob) {
    int i = blockIdx.x * 256 + threadIdx.x;
    {
        float4 v = reinterpret_cast<const float4*>(wq)[i];
        unsigned short* d = wqb + (size_t)i * 4;
        d[0] = f2bf(v.x); d[1] = f2bf(v.y); d[2] = f2bf(v.z); d[3] = f2bf(v.w);
    }
    if (i < 65536) {
        float4 v = reinterpret_cast<const float4*>(wo)[i];
        unsigned short* d = wob + (size_t)i * 4;
        d[0] = f2bf(v.x); d[1] = f2bf(v.y); d[2] = f2bf(v.z); d[3] = f2bf(v.w);
    }
}

// ---------------- K1: groupnorm stats (mean, rstd) per (b,group) ------------
__global__ __launch_bounds__(256) void gn_stats(
    const float* __restrict__ x, float2* __restrict__ stats) {
    __shared__ float ss[256], sq[256];
    int bg = blockIdx.x, t = threadIdx.x;
    const float4* p = reinterpret_cast<const float4*>(x + (size_t)bg * 65536);
    float s = 0.f, q = 0.f;
    for (int i = t; i < 16384; i += 256) {
        float4 v = p[i];
        s += v.x + v.y + v.z + v.w;
        q += v.x * v.x + v.y * v.y + v.z * v.z + v.w * v.w;
    }
    ss[t] = s; sq[t] = q; __syncthreads();
    for (int o = 128; o > 0; o >>= 1) {
        if (t < o) { ss[t] += ss[t + o]; sq[t] += sq[t + o]; }
        __syncthreads();
    }
    if (t == 0) {
        float mean = ss[0] * (1.f / 65536.f);
        float var  = sq[0] * (1.f / 65536.f) - mean * mean;
        stats[bg] = make_float2(mean, rsqrtf(var + 1e-5f));
    }
}

// ---------------- K2: normalize + transpose -> xnT[b][n][c] bf16 ------------
__global__ __launch_bounds__(256) void gn_norm_t(
    const float* __restrict__ x, const float* __restrict__ gamma,
    const float* __restrict__ beta, const float2* __restrict__ stats,
    unsigned short* __restrict__ xnT) {
    __shared__ unsigned short tile[64 * 72];
    int t = threadIdx.x;
    int jt = blockIdx.x, ct = blockIdx.y, b = blockIdx.z;
    int c = t >> 2, jseg = (t & 3) * 16;
    float2 ms = stats[b * 8 + ct];
    int ch = ct * 64 + c;
    float g  = gamma[ch] * ms.y;
    float bb = beta[ch] - ms.x * g;
    const float* src = x + ((size_t)(b * 512 + ch)) * 1024 + jt * 64 + jseg;
    float4 v0 = *(const float4*)(src);
    float4 v1 = *(const float4*)(src + 4);
    float4 v2 = *(const float4*)(src + 8);
    float4 v3 = *(const float4*)(src + 12);
    float vv[16] = {v0.x,v0.y,v0.z,v0.w, v1.x,v1.y,v1.z,v1.w,
                    v2.x,v2.y,v2.z,v2.w, v3.x,v3.y,v3.z,v3.w};
    #pragma unroll
    for (int e = 0; e < 16; ++e)
        tile[(jseg + e) * 72 + c] = f2bf(fmaf(vv[e], g, bb));
    __syncthreads();
    int j = t >> 2, cseg = (t & 3) * 16;
    unsigned short* dst = xnT + ((size_t)b * 1024 + jt * 64 + j) * 512 + ct * 64 + cseg;
    bf16x8 a0 = *(const bf16x8*)&tile[j * 72 + cseg];
    bf16x8 a1 = *(const bf16x8*)&tile[j * 72 + cseg + 8];
    *(bf16x8*)dst = a0;
    *(bf16x8*)(dst + 8) = a1;
}

// ---------------- K3: QKV GEMM -> qT (scaled), kT, v ------------------------
// A = Wqkv bf16 [1536][512] row-major; B = xnT[b] [1024 j][512 c] row-major.
// qT,kT: [b*8+h][i/j][dd]  (dd contiguous);  v: [b*8+h][dd][j].
// Q pre-scaled by 0.125 * log2(e) so attention softmax runs in exp2 domain.
__global__ __launch_bounds__(256) void qkv_gemm(
    const unsigned short* __restrict__ W, const unsigned short* __restrict__ xnT,
    unsigned short* __restrict__ qT, unsigned short* __restrict__ kT,
    unsigned short* __restrict__ vK) {
    __shared__ unsigned short a_t[128 * 72];
    __shared__ unsigned short b_t[128 * 72];
    int t = threadIdx.x, w = t >> 6, l = t & 63, lr = l & 15, lg = l >> 4;
    int jt = blockIdx.x, mt = blockIdx.y, b = blockIdx.z;
    int o0 = mt * 128, j0 = jt * 128;
    int wr = w >> 1, wc = w & 1;
    const unsigned short* Bsrc = xnT + (size_t)b * 1024 * 512;
    f32x4 acc[4][4] = {};
    int srow = t >> 1, sseg = (t & 1) * 32;
    for (int kk = 0; kk < 512; kk += 64) {
        const unsigned short* ga = W    + (size_t)(o0 + srow) * 512 + kk + sseg;
        const unsigned short* gb = Bsrc + (size_t)(j0 + srow) * 512 + kk + sseg;
        bf16x8 a0 = *(const bf16x8*)ga,        a1 = *(const bf16x8*)(ga + 8);
        bf16x8 a2 = *(const bf16x8*)(ga + 16), a3 = *(const bf16x8*)(ga + 24);
        bf16x8 c0 = *(const bf16x8*)gb,        c1 = *(const bf16x8*)(gb + 8);
        bf16x8 c2 = *(const bf16x8*)(gb + 16), c3 = *(const bf16x8*)(gb + 24);
        *(bf16x8*)&a_t[srow * 72 + sseg]      = a0;
        *(bf16x8*)&a_t[srow * 72 + sseg + 8]  = a1;
        *(bf16x8*)&a_t[srow * 72 + sseg + 16] = a2;
        *(bf16x8*)&a_t[srow * 72 + sseg + 24] = a3;
        *(bf16x8*)&b_t[srow * 72 + sseg]      = c0;
        *(bf16x8*)&b_t[srow * 72 + sseg + 8]  = c1;
        *(bf16x8*)&b_t[srow * 72 + sseg + 16] = c2;
        *(bf16x8*)&b_t[srow * 72 + sseg + 24] = c3;
        __syncthreads();
        #pragma unroll
        for (int ks = 0; ks < 2; ++ks) {
            bf16x8 af[4], bfr[4];
            #pragma unroll
            for (int m = 0; m < 4; ++m)
                af[m] = *(const bf16x8*)&a_t[(wr * 64 + m * 16 + lr) * 72 + ks * 32 + lg * 8];
            #pragma unroll
            for (int n = 0; n < 4; ++n)
                bfr[n] = *(const bf16x8*)&b_t[(wc * 64 + n * 16 + lr) * 72 + ks * 32 + lg * 8];
            #pragma unroll
            for (int m = 0; m < 4; ++m)
                #pragma unroll
                for (int n = 0; n < 4; ++n)
                    acc[m][n] = MFMA16(af[m], bfr[n], acc[m][n]);
        }
        __syncthreads();
    }
    int part = mt >> 2;                       // 0=q, 1=k, 2=v
    int hh = ((mt * 2) + wr) & 7;             // head for this wave-row half
    if (part < 2) {
        unsigned short* dst = (part == 0) ? qT : kT;
        float sc = (part == 0) ? 0.1803368801f : 1.0f;  // 0.125*log2(e)
        #pragma unroll
        for (int m = 0; m < 4; ++m)
            #pragma unroll
            for (int n = 0; n < 4; ++n) {
                int j = j0 + wc * 64 + n * 16 + lr;
                u16x4 pkt;
                pkt[0] = f2bf(acc[m][n][0] * sc);
                pkt[1] = f2bf(acc[m][n][1] * sc);
                pkt[2] = f2bf(acc[m][n][2] * sc);
                pkt[3] = f2bf(acc[m][n][3] * sc);
                *(u16x4*)&dst[(((size_t)(b * 8 + hh)) * 1024 + j) * 64 + m * 16 + lg * 4] = pkt;
            }
    } else {
        #pragma unroll
        for (int m = 0; m < 4; ++m)
            #pragma unroll
            for (int n = 0; n < 4; ++n)
                #pragma unroll
                for (int r = 0; r < 4; ++r) {
                    int dd = m * 16 + lg * 4 + r;
                    int j = j0 + wc * 64 + n * 16 + lr;
                    vK[(((size_t)(b * 8 + hh)) * 64 + dd) * 1024 + j] = f2bf(acc[m][n][r]);
                }
    }
}

// ---------------- K4: flash attention, barrier-free -------------------------
// Each lane's K/V MFMA fragment is a contiguous 16B chunk of kT/vK — load
// directly from global (L2-resident, XCD-swizzled). LDS only for the
// wave-private P transpose round-trip; NO __syncthreads anywhere.
__global__ __launch_bounds__(256, 4) void attn_kern(
    const unsigned short* __restrict__ qT, const unsigned short* __restrict__ kT,
    const unsigned short* __restrict__ vK, unsigned short* __restrict__ o_t) {
    __shared__ unsigned short p_s[4 * 16 * 72];   // per-wave [i][j]
    int t = threadIdx.x, w = t >> 6, l = t & 63, lr = l & 15, lg = (l >> 4) & 3;
    // XCD-chunked swizzle: 128 consecutive decoded blocks (2 bh) per XCD
    int id = blockIdx.x;
    int lin = (id & 7) * 128 + (id >> 3);
    int qt = lin & 15, bh = lin >> 4;
    int b = bh >> 3, h = bh & 7;
    const unsigned short* qb = qT + (size_t)bh * 1024 * 64;
    const unsigned short* kb = kT + (size_t)bh * 1024 * 64;
    const unsigned short* vb = vK + (size_t)bh * 64 * 1024;
    int i0 = qt * 64 + w * 16;

    // Q fragments: A[row=i=lr][k=dd], dd = kt*32 + lg*8 + e  (b128 loads)
    bf16x8 aq[2];
    #pragma unroll
    for (int kt = 0; kt < 2; ++kt)
        aq[kt] = *(const bf16x8*)&qb[(size_t)(i0 + lr) * 64 + kt * 32 + lg * 8];

    bf16x8 ones;
    #pragma unroll
    for (int e = 0; e < 8; ++e) ones[e] = (short)0x3F80;   // bf16 1.0

    float m8[4];
    #pragma unroll
    for (int r = 0; r < 4; ++r) m8[r] = -3.0e38f;
    f32x4 accO[4] = {};
    f32x4 accL = {};
    unsigned short* pw = p_s + w * (16 * 72);

    // per-lane direct K/V fragment base addresses
    const unsigned short* kfrag = kb + (size_t)lr * 64 + lg * 8;       // + j*64 + kt*32
    const unsigned short* vfrag = vb + (size_t)lr * 1024 + lg * 8;     // + dt*16*1024 + j0t + kj*32

    for (int tile = 0; tile < 16; ++tile) {
        int j0t = tile * 64;

        // K fragments direct from global: row j = j0t + jt*16 + lr
        bf16x8 bk[2][4];
        #pragma unroll
        for (int kt = 0; kt < 2; ++kt)
            #pragma unroll
            for (int jt = 0; jt < 4; ++jt)
                bk[kt][jt] = *(const bf16x8*)&kfrag[(size_t)(j0t + jt * 16) * 64 + kt * 32];

        // V fragments direct from global: row dd = dt*16 + lr, col j0t + kj*32 + lg*8
        bf16x8 bv[2][4];
        #pragma unroll
        for (int kj = 0; kj < 2; ++kj)
            #pragma unroll
            for (int dt = 0; dt < 4; ++dt)
                bv[kj][dt] = *(const bf16x8*)&vfrag[(size_t)(dt * 16) * 1024 + j0t + kj * 32];

        // S = Q K^T  (log2 domain)
        f32x4 s[4] = {};
        #pragma unroll
        for (int kt = 0; kt < 2; ++kt)
            #pragma unroll
            for (int jt = 0; jt < 4; ++jt)
                s[jt] = MFMA16(aq[kt], bk[kt][jt], s[jt]);

        // per-row tile max via DPP; defer-max: rescale only on growth
        float sm[4];
        #pragma unroll
        for (int r = 0; r < 4; ++r) {
            float v0 = fmaxf(fmaxf(s[0][r], s[1][r]), fmaxf(s[2][r], s[3][r]));
            v0 = fmaxf(v0, ROR16(v0, 1));
            v0 = fmaxf(v0, ROR16(v0, 2));
            v0 = fmaxf(v0, ROR16(v0, 4));
            v0 = fmaxf(v0, ROR16(v0, 8));
            sm[r] = v0;
        }
        float g = fmaxf(fmaxf(sm[0] - m8[0], sm[1] - m8[1]),
                        fmaxf(sm[2] - m8[2], sm[3] - m8[3]));
        if (__any(g > 11.0f)) {
            #pragma unroll
            for (int r = 0; r < 4; ++r) {
                float mn = fmaxf(m8[r], sm[r]);
                float al = EXP2(m8[r] - mn);
                accL[r] *= al;
                #pragma unroll
                for (int dt = 0; dt < 4; ++dt) accO[dt][r] *= al;
                m8[r] = mn;
            }
        }

        // P = exp2(S - m), pack to bf16 in wave-private LDS (no barrier:
        // wave-internal dependency, compiler inserts lgkmcnt)
        #pragma unroll
        for (int jt = 0; jt < 4; ++jt) {
            unsigned u01 = pk2(EXP2(s[jt][0] - m8[0]), EXP2(s[jt][1] - m8[1]));
            unsigned u23 = pk2(EXP2(s[jt][2] - m8[2]), EXP2(s[jt][3] - m8[3]));
            int col = jt * 16 + lr;
            pw[(lg * 4 + 0) * 72 + col] = (unsigned short)u01;
            pw[(lg * 4 + 1) * 72 + col] = (unsigned short)(u01 >> 16);
            pw[(lg * 4 + 2) * 72 + col] = (unsigned short)u23;
            pw[(lg * 4 + 3) * 72 + col] = (unsigned short)(u23 >> 16);
        }

        // O += P V^T ; L += P * 1  (row sums via matrix pipe)
        #pragma unroll
        for (int kj = 0; kj < 2; ++kj) {
            bf16x8 pa = *(const bf16x8*)&pw[lr * 72 + kj * 32 + lg * 8];
            accL = MFMA16(pa, ones, accL);
            #pragma unroll
            for (int dt = 0; dt < 4; ++dt)
                accO[dt] = MFMA16(pa, bv[kj][dt], accO[dt]);
        }
    }

    // epilogue: o_t[b][i][h*64+dd] = O[i][dd] / l
    float inv[4];
    #pragma unroll
    for (int r = 0; r < 4; ++r) inv[r] = 1.0f / accL[r];
    #pragma unroll
    for (int dt = 0; dt < 4; ++dt)
        #pragma unroll
        for (int r = 0; r < 4; ++r) {
            int i = i0 + lg * 4 + r;
            o_t[((size_t)b * 1024 + i) * 512 + h * 64 + dt * 16 + lr] =
                f2bf(accO[dt][r] * inv[r]);
        }
}

// ---------------- K5: proj GEMM + bias + residual(xn) -----------------------
__global__ __launch_bounds__(256) void proj_gemm(
    const unsigned short* __restrict__ W, const unsigned short* __restrict__ o_t,
    const float* __restrict__ b_out, const float* __restrict__ x,
    const float* __restrict__ gamma, const float* __restrict__ beta,
    const float2* __restrict__ stats, float* __restrict__ out) {
    __shared__ unsigned short a_t[128 * 72];
    __shared__ unsigned short b_t[128 * 72];
    int t = threadIdx.x, w = t >> 6, l = t & 63, lr = l & 15, lg = l >> 4;
    int jt = blockIdx.x, mt = blockIdx.y, b = blockIdx.z;
    int o0 = mt * 128, j0 = jt * 128;
    int wr = w >> 1, wc = w & 1;
    const unsigned short* Bsrc = o_t + (size_t)b * 1024 * 512;
    f32x4 acc[4][4] = {};
    int srow = t >> 1, sseg = (t & 1) * 32;
    for (int kk = 0; kk < 512; kk += 64) {
        const unsigned short* ga = W    + (size_t)(o0 + srow) * 512 + kk + sseg;
        const unsigned short* gb = Bsrc + (size_t)(j0 + srow) * 512 + kk + sseg;
        bf16x8 a0 = *(const bf16x8*)ga,        a1 = *(const bf16x8*)(ga + 8);
        bf16x8 a2 = *(const bf16x8*)(ga + 16), a3 = *(const bf16x8*)(ga + 24);
        bf16x8 c0 = *(const bf16x8*)gb,        c1 = *(const bf16x8*)(gb + 8);
        bf16x8 c2 = *(const bf16x8*)(gb + 16), c3 = *(const bf16x8*)(gb + 24);
        *(bf16x8*)&a_t[srow * 72 + sseg]      = a0;
        *(bf16x8*)&a_t[srow * 72 + sseg + 8]  = a1;
        *(bf16x8*)&a_t[srow * 72 + sseg + 16] = a2;
        *(bf16x8*)&a_t[srow * 72 + sseg + 24] = a3;
        *(bf16x8*)&b_t[srow * 72 + sseg]      = c0;
        *(bf16x8*)&b_t[srow * 72 + sseg + 8]  = c1;
        *(bf16x8*)&b_t[srow * 72 + sseg + 16] = c2;
        *(bf16x8*)&b_t[srow * 72 + sseg + 24] = c3;
        __syncthreads();
        #pragma unroll
        for (int ks = 0; ks < 2; ++ks) {
            bf16x8 af[4], bfr[4];
            #pragma unroll
            for (int m = 0; m < 4; ++m)
                af[m] = *(const bf16x8*)&a_t[(wr * 64 + m * 16 + lr) * 72 + ks * 32 + lg * 8];
            #pragma unroll
            for (int n = 0; n < 4; ++n)
                bfr[n] = *(const bf16x8*)&b_t[(wc * 64 + n * 16 + lr) * 72 + ks * 32 + lg * 8];
            #pragma unroll
            for (int m = 0; m < 4; ++m)
                #pragma unroll
                for (int n = 0; n < 4; ++n)
                    acc[m][n] = MFMA16(af[m], bfr[n], acc[m][n]);
        }
        __syncthreads();
    }
    #pragma unroll
    for (int m = 0; m < 4; ++m)
        #pragma unroll
        for (int r = 0; r < 4; ++r) {
            int o = o0 + wr * 64 + m * 16 + lg * 4 + r;
            float2 ms = stats[b * 8 + (o >> 6)];
            float g  = gamma[o] * ms.y;
            float bb = beta[o] - ms.x * g + b_out[o];
            const float* xr = x + ((size_t)b * 512 + o) * 1024;
            #pragma unroll
            for (int n = 0; n < 4; ++n) {
                int j = j0 + wc * 64 + n * 16 + lr;
                float xn = fmaf(xr[j], g, bb);
                out[((size_t)b * 512 + o) * 1024 + j] = acc[m][n][r] + xn;
            }
        }
}

// ---------------------------------------------------------------------------
extern "C" void kernel_launch(void* const* d_in, const int* in_sizes, int n_in,
                              void* d_out, int out_size, void* d_ws, size_t ws_size,
                              hipStream_t stream) {
    const float* x     = (const float*)d_in[0];
    const float* gamma = (const float*)d_in[1];
    const float* beta  = (const float*)d_in[2];
    const float* w_qkv = (const float*)d_in[3];
    const float* w_out = (const float*)d_in[4];
    const float* b_out = (const float*)d_in[5];
    float* out = (float*)d_out;

    char* ws = (char*)d_ws;
    unsigned short* wqb   = (unsigned short*)(ws);                    // 1.5 MB
    unsigned short* wob   = (unsigned short*)(ws + 0x180000);         // 0.5 MB
    float2*         stats = (float2*)(ws + 0x200000);                 // 512 B
    unsigned short* xnT   = (unsigned short*)(ws + 0x210000);         // 8 MB
    unsigned short* qT    = (unsigned short*)(ws + 0xA10000);         // 8 MB
    unsigned short* kT    = (unsigned short*)(ws + 0x1210000);        // 8 MB
    unsigned short* vK    = (unsigned short*)(ws + 0x1A10000);        // 8 MB
    unsigned short* o_t   = (unsigned short*)(ws + 0x2210000);        // 8 MB
    // total ~44.1 MB

    cvt_weights<<<768, 256, 0, stream>>>(w_qkv, w_out, wqb, wob);
    gn_stats<<<64, 256, 0, stream>>>(x, stats);
    gn_norm_t<<<dim3(16, 8, 8), 256, 0, stream>>>(x, gamma, beta, stats, xnT);
    qkv_gemm<<<dim3(8, 12, 8), 256, 0, stream>>>(wqb, xnT, qT, kT, vK);
    attn_kern<<<1024, 256, 0, stream>>>(qT, kT, vK, o_t);
    proj_gemm<<<dim3(8, 4, 8), 256, 0, stream>>>(wob, o_t, b_out, x, gamma, beta, stats, out);
}

// Round 9
// 112.517 us; speedup vs baseline: 1.6857x; 1.6857x over previous
//
#include <hip/hip_runtime.h>
#include <hip/hip_bf16.h>

// ---------------------------------------------------------------------------
// Fused: GroupNorm -> QKV (1x1 conv) -> 8-head attention (n=1024,d=64)
//        -> proj (1x1 conv) + bias + residual(xn)
// b=8, c=512, n=1024, GROUPS=8, HEADS=8, dim_head=64. bf16 MFMA, fp32 accum.
// R9: revert R8 (LDS staging restored — global-direct was latency-bound).
//     Attention now 32 q-rows/wave (2 i-tiles), grid 512: halves LDS
//     fragment-read traffic, staging loads, and barriers per unit work;
//     bk/bv reads shared across both i-tiles.
// ---------------------------------------------------------------------------

typedef short bf16x8 __attribute__((ext_vector_type(8)));
typedef float f32x4 __attribute__((ext_vector_type(4)));
typedef unsigned short u16x4 __attribute__((ext_vector_type(4)));

#define MFMA16(a, b, c) __builtin_amdgcn_mfma_f32_16x16x32_bf16(a, b, c, 0, 0, 0)
#define EXP2(x) __builtin_amdgcn_exp2f(x)
// rotate-right by N within each 16-lane row (pure VALU DPP)
#define ROR16(v, N) __int_as_float(__builtin_amdgcn_mov_dpp(__float_as_int(v), 0x120 + (N), 0xF, 0xF, false))

__device__ __forceinline__ unsigned short f2bf(float f) {
    unsigned u = __float_as_uint(f);
    u += 0x7fffu + ((u >> 16) & 1u);   // round-to-nearest-even
    return (unsigned short)(u >> 16);
}

// pack two fp32 -> u32 of two bf16 (lo=a, hi=b), RNE via HIP intrinsic
__device__ __forceinline__ unsigned pk2(float a, float b) {
    __hip_bfloat162 h = __float22bfloat162_rn(float2{a, b});
    unsigned r;
    __builtin_memcpy(&r, &h, 4);
    return r;
}

// ---------------- K0: convert weights fp32 -> bf16 -------------------------
__global__ __launch_bounds__(256) void cvt_weights(
    const float* __restrict__ wq, const float* __restrict__ wo,
    unsigned short* __restrict__ wqb, unsigned short* __restrict__ wob) {
    int i = blockIdx.x * 256 + threadIdx.x;
    {
        float4 v = reinterpret_cast<const float4*>(wq)[i];
        unsigned short* d = wqb + (size_t)i * 4;
        d[0] = f2bf(v.x); d[1] = f2bf(v.y); d[2] = f2bf(v.z); d[3] = f2bf(v.w);
    }
    if (i < 65536) {
        float4 v = reinterpret_cast<const float4*>(wo)[i];
        unsigned short* d = wob + (size_t)i * 4;
        d[0] = f2bf(v.x); d[1] = f2bf(v.y); d[2] = f2bf(v.z); d[3] = f2bf(v.w);
    }
}

// ---------------- K1: groupnorm stats (mean, rstd) per (b,group) ------------
__global__ __launch_bounds__(256) void gn_stats(
    const float* __restrict__ x, float2* __restrict__ stats) {
    __shared__ float ss[256], sq[256];
    int bg = blockIdx.x, t = threadIdx.x;
    const float4* p = reinterpret_cast<const float4*>(x + (size_t)bg * 65536);
    float s = 0.f, q = 0.f;
    for (int i = t; i < 16384; i += 256) {
        float4 v = p[i];
        s += v.x + v.y + v.z + v.w;
        q += v.x * v.x + v.y * v.y + v.z * v.z + v.w * v.w;
    }
    ss[t] = s; sq[t] = q; __syncthreads();
    for (int o = 128; o > 0; o >>= 1) {
        if (t < o) { ss[t] += ss[t + o]; sq[t] += sq[t + o]; }
        __syncthreads();
    }
    if (t == 0) {
        float mean = ss[0] * (1.f / 65536.f);
        float var  = sq[0] * (1.f / 65536.f) - mean * mean;
        stats[bg] = make_float2(mean, rsqrtf(var + 1e-5f));
    }
}

// ---------------- K2: normalize + transpose -> xnT[b][n][c] bf16 ------------
__global__ __launch_bounds__(256) void gn_norm_t(
    const float* __restrict__ x, const float* __restrict__ gamma,
    const float* __restrict__ beta, const float2* __restrict__ stats,
    unsigned short* __restrict__ xnT) {
    __shared__ unsigned short tile[64 * 72];
    int t = threadIdx.x;
    int jt = blockIdx.x, ct = blockIdx.y, b = blockIdx.z;
    int c = t >> 2, jseg = (t & 3) * 16;
    float2 ms = stats[b * 8 + ct];
    int ch = ct * 64 + c;
    float g  = gamma[ch] * ms.y;
    float bb = beta[ch] - ms.x * g;
    const float* src = x + ((size_t)(b * 512 + ch)) * 1024 + jt * 64 + jseg;
    float4 v0 = *(const float4*)(src);
    float4 v1 = *(const float4*)(src + 4);
    float4 v2 = *(const float4*)(src + 8);
    float4 v3 = *(const float4*)(src + 12);
    float vv[16] = {v0.x,v0.y,v0.z,v0.w, v1.x,v1.y,v1.z,v1.w,
                    v2.x,v2.y,v2.z,v2.w, v3.x,v3.y,v3.z,v3.w};
    #pragma unroll
    for (int e = 0; e < 16; ++e)
        tile[(jseg + e) * 72 + c] = f2bf(fmaf(vv[e], g, bb));
    __syncthreads();
    int j = t >> 2, cseg = (t & 3) * 16;
    unsigned short* dst = xnT + ((size_t)b * 1024 + jt * 64 + j) * 512 + ct * 64 + cseg;
    bf16x8 a0 = *(const bf16x8*)&tile[j * 72 + cseg];
    bf16x8 a1 = *(const bf16x8*)&tile[j * 72 + cseg + 8];
    *(bf16x8*)dst = a0;
    *(bf16x8*)(dst + 8) = a1;
}

// ---------------- K3: QKV GEMM -> qT (scaled), kT, v ------------------------
// A = Wqkv bf16 [1536][512] row-major; B = xnT[b] [1024 j][512 c] row-major.
// qT,kT: [b*8+h][i/j][dd]  (dd contiguous);  v: [b*8+h][dd][j].
// Q pre-scaled by 0.125 * log2(e) so attention softmax runs in exp2 domain.
__global__ __launch_bounds__(256) void qkv_gemm(
    const unsigned short* __restrict__ W, const unsigned short* __restrict__ xnT,
    unsigned short* __restrict__ qT, unsigned short* __restrict__ kT,
    unsigned short* __restrict__ vK) {
    __shared__ unsigned short a_t[128 * 72];
    __shared__ unsigned short b_t[128 * 72];
    int t = threadIdx.x, w = t >> 6, l = t & 63, lr = l & 15, lg = l >> 4;
    int jt = blockIdx.x, mt = blockIdx.y, b = blockIdx.z;
    int o0 = mt * 128, j0 = jt * 128;
    int wr = w >> 1, wc = w & 1;
    const unsigned short* Bsrc = xnT + (size_t)b * 1024 * 512;
    f32x4 acc[4][4] = {};
    int srow = t >> 1, sseg = (t & 1) * 32;
    for (int kk = 0; kk < 512; kk += 64) {
        const unsigned short* ga = W    + (size_t)(o0 + srow) * 512 + kk + sseg;
        const unsigned short* gb = Bsrc + (size_t)(j0 + srow) * 512 + kk + sseg;
        bf16x8 a0 = *(const bf16x8*)ga,        a1 = *(const bf16x8*)(ga + 8);
        bf16x8 a2 = *(const bf16x8*)(ga + 16), a3 = *(const bf16x8*)(ga + 24);
        bf16x8 c0 = *(const bf16x8*)gb,        c1 = *(const bf16x8*)(gb + 8);
        bf16x8 c2 = *(const bf16x8*)(gb + 16), c3 = *(const bf16x8*)(gb + 24);
        *(bf16x8*)&a_t[srow * 72 + sseg]      = a0;
        *(bf16x8*)&a_t[srow * 72 + sseg + 8]  = a1;
        *(bf16x8*)&a_t[srow * 72 + sseg + 16] = a2;
        *(bf16x8*)&a_t[srow * 72 + sseg + 24] = a3;
        *(bf16x8*)&b_t[srow * 72 + sseg]      = c0;
        *(bf16x8*)&b_t[srow * 72 + sseg + 8]  = c1;
        *(bf16x8*)&b_t[srow * 72 + sseg + 16] = c2;
        *(bf16x8*)&b_t[srow * 72 + sseg + 24] = c3;
        __syncthreads();
        #pragma unroll
        for (int ks = 0; ks < 2; ++ks) {
            bf16x8 af[4], bfr[4];
            #pragma unroll
            for (int m = 0; m < 4; ++m)
                af[m] = *(const bf16x8*)&a_t[(wr * 64 + m * 16 + lr) * 72 + ks * 32 + lg * 8];
            #pragma unroll
            for (int n = 0; n < 4; ++n)
                bfr[n] = *(const bf16x8*)&b_t[(wc * 64 + n * 16 + lr) * 72 + ks * 32 + lg * 8];
            #pragma unroll
            for (int m = 0; m < 4; ++m)
                #pragma unroll
                for (int n = 0; n < 4; ++n)
                    acc[m][n] = MFMA16(af[m], bfr[n], acc[m][n]);
        }
        __syncthreads();
    }
    int part = mt >> 2;                       // 0=q, 1=k, 2=v
    int hh = ((mt * 2) + wr) & 7;             // head for this wave-row half
    if (part < 2) {
        unsigned short* dst = (part == 0) ? qT : kT;
        float sc = (part == 0) ? 0.1803368801f : 1.0f;  // 0.125*log2(e)
        #pragma unroll
        for (int m = 0; m < 4; ++m)
            #pragma unroll
            for (int n = 0; n < 4; ++n) {
                int j = j0 + wc * 64 + n * 16 + lr;
                u16x4 pkt;
                pkt[0] = f2bf(acc[m][n][0] * sc);
                pkt[1] = f2bf(acc[m][n][1] * sc);
                pkt[2] = f2bf(acc[m][n][2] * sc);
                pkt[3] = f2bf(acc[m][n][3] * sc);
                *(u16x4*)&dst[(((size_t)(b * 8 + hh)) * 1024 + j) * 64 + m * 16 + lg * 4] = pkt;
            }
    } else {
        #pragma unroll
        for (int m = 0; m < 4; ++m)
            #pragma unroll
            for (int n = 0; n < 4; ++n)
                #pragma unroll
                for (int r = 0; r < 4; ++r) {
                    int dd = m * 16 + lg * 4 + r;
                    int j = j0 + wc * 64 + n * 16 + lr;
                    vK[(((size_t)(b * 8 + hh)) * 64 + dd) * 1024 + j] = f2bf(acc[m][n][r]);
                }
    }
}

// ---------------- K4: flash attention, 4 waves x 32 q-rows ------------------
// LDS-staged K/V shared by all waves; two independent 16-row i-tiles per wave
// share the bk/bv fragment reads (halves LDS read traffic per unit work).
__global__ __launch_bounds__(256, 2) void attn_kern(
    const unsigned short* __restrict__ qT, const unsigned short* __restrict__ kT,
    const unsigned short* __restrict__ vK, unsigned short* __restrict__ o_t) {
    __shared__ unsigned short k_t[64 * 72];       // [j][dd]
    __shared__ unsigned short v_s[64 * 72];       // [dd][j]
    __shared__ unsigned short p_s[4 * 32 * 72];   // per-wave [i][j]
    int t = threadIdx.x, w = t >> 6, l = t & 63, lr = l & 15, lg = (l >> 4) & 3;
    // XCD-chunked swizzle: 64 consecutive decoded blocks (1 bh) per XCD
    int id = blockIdx.x;
    int lin = (id & 7) * 64 + (id >> 3);
    int qt = lin & 7, bh = lin >> 3;
    int b = bh >> 3, h = bh & 7;
    const unsigned short* qb = qT + (size_t)bh * 1024 * 64;
    const unsigned short* kb = kT + (size_t)bh * 1024 * 64;
    const unsigned short* vb = vK + (size_t)bh * 64 * 1024;
    int i0 = qt * 128 + w * 32;

    // Q fragments: A[row=i][k=dd], rows i0 + it*16 + lr  (b128 loads)
    bf16x8 aq[2][2];
    #pragma unroll
    for (int it = 0; it < 2; ++it)
        #pragma unroll
        for (int kt = 0; kt < 2; ++kt)
            aq[it][kt] = *(const bf16x8*)&qb[(size_t)(i0 + it * 16 + lr) * 64 + kt * 32 + lg * 8];

    bf16x8 ones;
    #pragma unroll
    for (int e = 0; e < 8; ++e) ones[e] = (short)0x3F80;   // bf16 1.0

    float m8[2][4];
    #pragma unroll
    for (int it = 0; it < 2; ++it)
        #pragma unroll
        for (int r = 0; r < 4; ++r) m8[it][r] = -3.0e38f;
    f32x4 accO[2][4] = {};
    f32x4 accL[2] = {};
    unsigned short* pw = p_s + w * (32 * 72);

    // staging: thread t stages 32B of K and 32B of V per tile
    int srow = t >> 2, scol = (t & 3) * 16;
    const unsigned short* kg = kb + srow * 64 + scol;            // K row j=srow
    const unsigned short* vg = vb + (size_t)srow * 1024 + scol;  // V row dd=srow
    unsigned short* kw = &k_t[srow * 72 + scol];
    unsigned short* vw = &v_s[srow * 72 + scol];

    bf16x8 nk0 = *(const bf16x8*)kg,       nk1 = *(const bf16x8*)(kg + 8);
    bf16x8 nv0 = *(const bf16x8*)vg,       nv1 = *(const bf16x8*)(vg + 8);

    for (int tile = 0; tile < 16; ++tile) {
        __syncthreads();                       // prev tile reads complete
        *(bf16x8*)kw = nk0; *(bf16x8*)(kw + 8) = nk1;
        *(bf16x8*)vw = nv0; *(bf16x8*)(vw + 8) = nv1;
        if (tile < 15) {                       // prefetch next tile
            const unsigned short* kn = kg + (tile + 1) * 4096;
            const unsigned short* vn = vg + (tile + 1) * 64;
            nk0 = *(const bf16x8*)kn; nk1 = *(const bf16x8*)(kn + 8);
            nv0 = *(const bf16x8*)vn; nv1 = *(const bf16x8*)(vn + 8);
        }
        __syncthreads();                       // LDS visible

        // S = Q K^T  (log2 domain) — bk shared by both i-tiles
        f32x4 s[2][4] = {};
        #pragma unroll
        for (int kt = 0; kt < 2; ++kt) {
            bf16x8 bk[4];
            #pragma unroll
            for (int jt = 0; jt < 4; ++jt)
                bk[jt] = *(const bf16x8*)&k_t[(jt * 16 + lr) * 72 + kt * 32 + lg * 8];
            #pragma unroll
            for (int it = 0; it < 2; ++it)
                #pragma unroll
                for (int jt = 0; jt < 4; ++jt)
                    s[it][jt] = MFMA16(aq[it][kt], bk[jt], s[it][jt]);
        }

        // per-row tile max via DPP; defer-max: rescale only on growth
        float sm[2][4];
        float g = -3.0e38f;
        #pragma unroll
        for (int it = 0; it < 2; ++it)
            #pragma unroll
            for (int r = 0; r < 4; ++r) {
                float v0 = fmaxf(fmaxf(s[it][0][r], s[it][1][r]),
                                 fmaxf(s[it][2][r], s[it][3][r]));
                v0 = fmaxf(v0, ROR16(v0, 1));
                v0 = fmaxf(v0, ROR16(v0, 2));
                v0 = fmaxf(v0, ROR16(v0, 4));
                v0 = fmaxf(v0, ROR16(v0, 8));
                sm[it][r] = v0;
                g = fmaxf(g, v0 - m8[it][r]);
            }
        if (__any(g > 11.0f)) {
            #pragma unroll
            for (int it = 0; it < 2; ++it)
                #pragma unroll
                for (int r = 0; r < 4; ++r) {
                    float mn = fmaxf(m8[it][r], sm[it][r]);
                    float al = EXP2(m8[it][r] - mn);
                    accL[it][r] *= al;
                    #pragma unroll
                    for (int dt = 0; dt < 4; ++dt) accO[it][dt][r] *= al;
                    m8[it][r] = mn;
                }
        }

        // P = exp2(S - m), pack to bf16 in wave-private LDS
        #pragma unroll
        for (int it = 0; it < 2; ++it)
            #pragma unroll
            for (int jt = 0; jt < 4; ++jt) {
                unsigned u01 = pk2(EXP2(s[it][jt][0] - m8[it][0]),
                                   EXP2(s[it][jt][1] - m8[it][1]));
                unsigned u23 = pk2(EXP2(s[it][jt][2] - m8[it][2]),
                                   EXP2(s[it][jt][3] - m8[it][3]));
                int row = it * 16 + lg * 4;
                int col = jt * 16 + lr;
                pw[(row + 0) * 72 + col] = (unsigned short)u01;
                pw[(row + 1) * 72 + col] = (unsigned short)(u01 >> 16);
                pw[(row + 2) * 72 + col] = (unsigned short)u23;
                pw[(row + 3) * 72 + col] = (unsigned short)(u23 >> 16);
            }

        // O += P V^T ; L += P * 1  — bv shared by both i-tiles
        #pragma unroll
        for (int kj = 0; kj < 2; ++kj) {
            bf16x8 bv[4];
            #pragma unroll
            for (int dt = 0; dt < 4; ++dt)
                bv[dt] = *(const bf16x8*)&v_s[(dt * 16 + lr) * 72 + kj * 32 + lg * 8];
            #pragma unroll
            for (int it = 0; it < 2; ++it) {
                bf16x8 pa = *(const bf16x8*)&pw[(it * 16 + lr) * 72 + kj * 32 + lg * 8];
                accL[it] = MFMA16(pa, ones, accL[it]);
                #pragma unroll
                for (int dt = 0; dt < 4; ++dt)
                    accO[it][dt] = MFMA16(pa, bv[dt], accO[it][dt]);
            }
        }
    }

    // epilogue: o_t[b][i][h*64+dd] = O[i][dd] / l
    #pragma unroll
    for (int it = 0; it < 2; ++it) {
        float inv[4];
        #pragma unroll
        for (int r = 0; r < 4; ++r) inv[r] = 1.0f / accL[it][r];
        #pragma unroll
        for (int dt = 0; dt < 4; ++dt)
            #pragma unroll
            for (int r = 0; r < 4; ++r) {
                int i = i0 + it * 16 + lg * 4 + r;
                o_t[((size_t)b * 1024 + i) * 512 + h * 64 + dt * 16 + lr] =
                    f2bf(accO[it][dt][r] * inv[r]);
            }
    }
}

// ---------------- K5: proj GEMM + bias + residual(xn) -----------------------
__global__ __launch_bounds__(256) void proj_gemm(
    const unsigned short* __restrict__ W, const unsigned short* __restrict__ o_t,
    const float* __restrict__ b_out, const float* __restrict__ x,
    const float* __restrict__ gamma, const float* __restrict__ beta,
    const float2* __restrict__ stats, float* __restrict__ out) {
    __shared__ unsigned short a_t[128 * 72];
    __shared__ unsigned short b_t[128 * 72];
    int t = threadIdx.x, w = t >> 6, l = t & 63, lr = l & 15, lg = l >> 4;
    int jt = blockIdx.x, mt = blockIdx.y, b = blockIdx.z;
    int o0 = mt * 128, j0 = jt * 128;
    int wr = w >> 1, wc = w & 1;
    const unsigned short* Bsrc = o_t + (size_t)b * 1024 * 512;
    f32x4 acc[4][4] = {};
    int srow = t >> 1, sseg = (t & 1) * 32;
    for (int kk = 0; kk < 512; kk += 64) {
        const unsigned short* ga = W    + (size_t)(o0 + srow) * 512 + kk + sseg;
        const unsigned short* gb = Bsrc + (size_t)(j0 + srow) * 512 + kk + sseg;
        bf16x8 a0 = *(const bf16x8*)ga,        a1 = *(const bf16x8*)(ga + 8);
        bf16x8 a2 = *(const bf16x8*)(ga + 16), a3 = *(const bf16x8*)(ga + 24);
        bf16x8 c0 = *(const bf16x8*)gb,        c1 = *(const bf16x8*)(gb + 8);
        bf16x8 c2 = *(const bf16x8*)(gb + 16), c3 = *(const bf16x8*)(gb + 24);
        *(bf16x8*)&a_t[srow * 72 + sseg]      = a0;
        *(bf16x8*)&a_t[srow * 72 + sseg + 8]  = a1;
        *(bf16x8*)&a_t[srow * 72 + sseg + 16] = a2;
        *(bf16x8*)&a_t[srow * 72 + sseg + 24] = a3;
        *(bf16x8*)&b_t[srow * 72 + sseg]      = c0;
        *(bf16x8*)&b_t[srow * 72 + sseg + 8]  = c1;
        *(bf16x8*)&b_t[srow * 72 + sseg + 16] = c2;
        *(bf16x8*)&b_t[srow * 72 + sseg + 24] = c3;
        __syncthreads();
        #pragma unroll
        for (int ks = 0; ks < 2; ++ks) {
            bf16x8 af[4], bfr[4];
            #pragma unroll
            for (int m = 0; m < 4; ++m)
                af[m] = *(const bf16x8*)&a_t[(wr * 64 + m * 16 + lr) * 72 + ks * 32 + lg * 8];
            #pragma unroll
            for (int n = 0; n < 4; ++n)
                bfr[n] = *(const bf16x8*)&b_t[(wc * 64 + n * 16 + lr) * 72 + ks * 32 + lg * 8];
            #pragma unroll
            for (int m = 0; m < 4; ++m)
                #pragma unroll
                for (int n = 0; n < 4; ++n)
                    acc[m][n] = MFMA16(af[m], bfr[n], acc[m][n]);
        }
        __syncthreads();
    }
    #pragma unroll
    for (int m = 0; m < 4; ++m)
        #pragma unroll
        for (int r = 0; r < 4; ++r) {
            int o = o0 + wr * 64 + m * 16 + lg * 4 + r;
            float2 ms = stats[b * 8 + (o >> 6)];
            float g  = gamma[o] * ms.y;
            float bb = beta[o] - ms.x * g + b_out[o];
            const float* xr = x + ((size_t)b * 512 + o) * 1024;
            #pragma unroll
            for (int n = 0; n < 4; ++n) {
                int j = j0 + wc * 64 + n * 16 + lr;
                float xn = fmaf(xr[j], g, bb);
                out[((size_t)b * 512 + o) * 1024 + j] = acc[m][n][r] + xn;
            }
        }
}

// ---------------------------------------------------------------------------
extern "C" void kernel_launch(void* const* d_in, const int* in_sizes, int n_in,
                              void* d_out, int out_size, void* d_ws, size_t ws_size,
                              hipStream_t stream) {
    const float* x     = (const float*)d_in[0];
    const float* gamma = (const float*)d_in[1];
    const float* beta  = (const float*)d_in[2];
    const float* w_qkv = (const float*)d_in[3];
    const float* w_out = (const float*)d_in[4];
    const float* b_out = (const float*)d_in[5];
    float* out = (float*)d_out;

    char* ws = (char*)d_ws;
    unsigned short* wqb   = (unsigned short*)(ws);                    // 1.5 MB
    unsigned short* wob   = (unsigned short*)(ws + 0x180000);         // 0.5 MB
    float2*         stats = (float2*)(ws + 0x200000);                 // 512 B
    unsigned short* xnT   = (unsigned short*)(ws + 0x210000);         // 8 MB
    unsigned short* qT    = (unsigned short*)(ws + 0xA10000);         // 8 MB
    unsigned short* kT    = (unsigned short*)(ws + 0x1210000);        // 8 MB
    unsigned short* vK    = (unsigned short*)(ws + 0x1A10000);        // 8 MB
    unsigned short* o_t   = (unsigned short*)(ws + 0x2210000);        // 8 MB
    // total ~44.1 MB

    cvt_weights<<<768, 256, 0, stream>>>(w_qkv, w_out, wqb, wob);
    gn_stats<<<64, 256, 0, stream>>>(x, stats);
    gn_norm_t<<<dim3(16, 8, 8), 256, 0, stream>>>(x, gamma, beta, stats, xnT);
    qkv_gemm<<<dim3(8, 12, 8), 256, 0, stream>>>(wqb, xnT, qT, kT, vK);
    attn_kern<<<512, 256, 0, stream>>>(qT, kT, vK, o_t);
    proj_gemm<<<dim3(8, 4, 8), 256, 0, stream>>>(wob, o_t, b_out, x, gamma, beta, stats, out);
}

// Round 10
// 109.542 us; speedup vs baseline: 1.7314x; 1.0272x over previous
//
#include <hip/hip_runtime.h>
#include <hip/hip_bf16.h>

// ---------------------------------------------------------------------------
// Fused: GroupNorm -> QKV (1x1 conv) -> 8-head attention (n=1024,d=64)
//        -> proj (1x1 conv) + bias + residual(xn)
// b=8, c=512, n=1024, GROUPS=8, HEADS=8, dim_head=64. bf16 MFMA, fp32 accum.
// R10: attention K/V LDS double-buffered, ONE barrier per tile (writes of
//      tile t+1 overlap compute of tile t); 32 q-rows/wave, grid 512.
// ---------------------------------------------------------------------------

typedef short bf16x8 __attribute__((ext_vector_type(8)));
typedef float f32x4 __attribute__((ext_vector_type(4)));
typedef unsigned short u16x4 __attribute__((ext_vector_type(4)));

#define MFMA16(a, b, c) __builtin_amdgcn_mfma_f32_16x16x32_bf16(a, b, c, 0, 0, 0)
#define EXP2(x) __builtin_amdgcn_exp2f(x)
// rotate-right by N within each 16-lane row (pure VALU DPP)
#define ROR16(v, N) __int_as_float(__builtin_amdgcn_mov_dpp(__float_as_int(v), 0x120 + (N), 0xF, 0xF, false))

__device__ __forceinline__ unsigned short f2bf(float f) {
    unsigned u = __float_as_uint(f);
    u += 0x7fffu + ((u >> 16) & 1u);   // round-to-nearest-even
    return (unsigned short)(u >> 16);
}

// pack two fp32 -> u32 of two bf16 (lo=a, hi=b), RNE via HIP intrinsic
__device__ __forceinline__ unsigned pk2(float a, float b) {
    __hip_bfloat162 h = __float22bfloat162_rn(float2{a, b});
    unsigned r;
    __builtin_memcpy(&r, &h, 4);
    return r;
}

// ---------------- K0: convert weights fp32 -> bf16 -------------------------
__global__ __launch_bounds__(256) void cvt_weights(
    const float* __restrict__ wq, const float* __restrict__ wo,
    unsigned short* __restrict__ wqb, unsigned short* __restrict__ wob) {
    int i = blockIdx.x * 256 + threadIdx.x;
    {
        float4 v = reinterpret_cast<const float4*>(wq)[i];
        unsigned short* d = wqb + (size_t)i * 4;
        d[0] = f2bf(v.x); d[1] = f2bf(v.y); d[2] = f2bf(v.z); d[3] = f2bf(v.w);
    }
    if (i < 65536) {
        float4 v = reinterpret_cast<const float4*>(wo)[i];
        unsigned short* d = wob + (size_t)i * 4;
        d[0] = f2bf(v.x); d[1] = f2bf(v.y); d[2] = f2bf(v.z); d[3] = f2bf(v.w);
    }
}

// ---------------- K1: groupnorm stats (mean, rstd) per (b,group) ------------
__global__ __launch_bounds__(256) void gn_stats(
    const float* __restrict__ x, float2* __restrict__ stats) {
    __shared__ float ss[256], sq[256];
    int bg = blockIdx.x, t = threadIdx.x;
    const float4* p = reinterpret_cast<const float4*>(x + (size_t)bg * 65536);
    float s = 0.f, q = 0.f;
    for (int i = t; i < 16384; i += 256) {
        float4 v = p[i];
        s += v.x + v.y + v.z + v.w;
        q += v.x * v.x + v.y * v.y + v.z * v.z + v.w * v.w;
    }
    ss[t] = s; sq[t] = q; __syncthreads();
    for (int o = 128; o > 0; o >>= 1) {
        if (t < o) { ss[t] += ss[t + o]; sq[t] += sq[t + o]; }
        __syncthreads();
    }
    if (t == 0) {
        float mean = ss[0] * (1.f / 65536.f);
        float var  = sq[0] * (1.f / 65536.f) - mean * mean;
        stats[bg] = make_float2(mean, rsqrtf(var + 1e-5f));
    }
}

// ---------------- K2: normalize + transpose -> xnT[b][n][c] bf16 ------------
__global__ __launch_bounds__(256) void gn_norm_t(
    const float* __restrict__ x, const float* __restrict__ gamma,
    const float* __restrict__ beta, const float2* __restrict__ stats,
    unsigned short* __restrict__ xnT) {
    __shared__ unsigned short tile[64 * 72];
    int t = threadIdx.x;
    int jt = blockIdx.x, ct = blockIdx.y, b = blockIdx.z;
    int c = t >> 2, jseg = (t & 3) * 16;
    float2 ms = stats[b * 8 + ct];
    int ch = ct * 64 + c;
    float g  = gamma[ch] * ms.y;
    float bb = beta[ch] - ms.x * g;
    const float* src = x + ((size_t)(b * 512 + ch)) * 1024 + jt * 64 + jseg;
    float4 v0 = *(const float4*)(src);
    float4 v1 = *(const float4*)(src + 4);
    float4 v2 = *(const float4*)(src + 8);
    float4 v3 = *(const float4*)(src + 12);
    float vv[16] = {v0.x,v0.y,v0.z,v0.w, v1.x,v1.y,v1.z,v1.w,
                    v2.x,v2.y,v2.z,v2.w, v3.x,v3.y,v3.z,v3.w};
    #pragma unroll
    for (int e = 0; e < 16; ++e)
        tile[(jseg + e) * 72 + c] = f2bf(fmaf(vv[e], g, bb));
    __syncthreads();
    int j = t >> 2, cseg = (t & 3) * 16;
    unsigned short* dst = xnT + ((size_t)b * 1024 + jt * 64 + j) * 512 + ct * 64 + cseg;
    bf16x8 a0 = *(const bf16x8*)&tile[j * 72 + cseg];
    bf16x8 a1 = *(const bf16x8*)&tile[j * 72 + cseg + 8];
    *(bf16x8*)dst = a0;
    *(bf16x8*)(dst + 8) = a1;
}

// ---------------- K3: QKV GEMM -> qT (scaled), kT, v ------------------------
// A = Wqkv bf16 [1536][512] row-major; B = xnT[b] [1024 j][512 c] row-major.
// qT,kT: [b*8+h][i/j][dd]  (dd contiguous);  v: [b*8+h][dd][j].
// Q pre-scaled by 0.125 * log2(e) so attention softmax runs in exp2 domain.
__global__ __launch_bounds__(256) void qkv_gemm(
    const unsigned short* __restrict__ W, const unsigned short* __restrict__ xnT,
    unsigned short* __restrict__ qT, unsigned short* __restrict__ kT,
    unsigned short* __restrict__ vK) {
    __shared__ unsigned short a_t[128 * 72];
    __shared__ unsigned short b_t[128 * 72];
    int t = threadIdx.x, w = t >> 6, l = t & 63, lr = l & 15, lg = l >> 4;
    int jt = blockIdx.x, mt = blockIdx.y, b = blockIdx.z;
    int o0 = mt * 128, j0 = jt * 128;
    int wr = w >> 1, wc = w & 1;
    const unsigned short* Bsrc = xnT + (size_t)b * 1024 * 512;
    f32x4 acc[4][4] = {};
    int srow = t >> 1, sseg = (t & 1) * 32;
    for (int kk = 0; kk < 512; kk += 64) {
        const unsigned short* ga = W    + (size_t)(o0 + srow) * 512 + kk + sseg;
        const unsigned short* gb = Bsrc + (size_t)(j0 + srow) * 512 + kk + sseg;
        bf16x8 a0 = *(const bf16x8*)ga,        a1 = *(const bf16x8*)(ga + 8);
        bf16x8 a2 = *(const bf16x8*)(ga + 16), a3 = *(const bf16x8*)(ga + 24);
        bf16x8 c0 = *(const bf16x8*)gb,        c1 = *(const bf16x8*)(gb + 8);
        bf16x8 c2 = *(const bf16x8*)(gb + 16), c3 = *(const bf16x8*)(gb + 24);
        *(bf16x8*)&a_t[srow * 72 + sseg]      = a0;
        *(bf16x8*)&a_t[srow * 72 + sseg + 8]  = a1;
        *(bf16x8*)&a_t[srow * 72 + sseg + 16] = a2;
        *(bf16x8*)&a_t[srow * 72 + sseg + 24] = a3;
        *(bf16x8*)&b_t[srow * 72 + sseg]      = c0;
        *(bf16x8*)&b_t[srow * 72 + sseg + 8]  = c1;
        *(bf16x8*)&b_t[srow * 72 + sseg + 16] = c2;
        *(bf16x8*)&b_t[srow * 72 + sseg + 24] = c3;
        __syncthreads();
        #pragma unroll
        for (int ks = 0; ks < 2; ++ks) {
            bf16x8 af[4], bfr[4];
            #pragma unroll
            for (int m = 0; m < 4; ++m)
                af[m] = *(const bf16x8*)&a_t[(wr * 64 + m * 16 + lr) * 72 + ks * 32 + lg * 8];
            #pragma unroll
            for (int n = 0; n < 4; ++n)
                bfr[n] = *(const bf16x8*)&b_t[(wc * 64 + n * 16 + lr) * 72 + ks * 32 + lg * 8];
            #pragma unroll
            for (int m = 0; m < 4; ++m)
                #pragma unroll
                for (int n = 0; n < 4; ++n)
                    acc[m][n] = MFMA16(af[m], bfr[n], acc[m][n]);
        }
        __syncthreads();
    }
    int part = mt >> 2;                       // 0=q, 1=k, 2=v
    int hh = ((mt * 2) + wr) & 7;             // head for this wave-row half
    if (part < 2) {
        unsigned short* dst = (part == 0) ? qT : kT;
        float sc = (part == 0) ? 0.1803368801f : 1.0f;  // 0.125*log2(e)
        #pragma unroll
        for (int m = 0; m < 4; ++m)
            #pragma unroll
            for (int n = 0; n < 4; ++n) {
                int j = j0 + wc * 64 + n * 16 + lr;
                u16x4 pkt;
                pkt[0] = f2bf(acc[m][n][0] * sc);
                pkt[1] = f2bf(acc[m][n][1] * sc);
                pkt[2] = f2bf(acc[m][n][2] * sc);
                pkt[3] = f2bf(acc[m][n][3] * sc);
                *(u16x4*)&dst[(((size_t)(b * 8 + hh)) * 1024 + j) * 64 + m * 16 + lg * 4] = pkt;
            }
    } else {
        #pragma unroll
        for (int m = 0; m < 4; ++m)
            #pragma unroll
            for (int n = 0; n < 4; ++n)
                #pragma unroll
                for (int r = 0; r < 4; ++r) {
                    int dd = m * 16 + lg * 4 + r;
                    int j = j0 + wc * 64 + n * 16 + lr;
                    vK[(((size_t)(b * 8 + hh)) * 64 + dd) * 1024 + j] = f2bf(acc[m][n][r]);
                }
    }
}

// ---------------- K4: flash attention, 4 waves x 32 q-rows, dbuf LDS --------
// One barrier per K/V tile: {barrier; write buf[(t+1)&1]; prefetch t+2;
// compute tile t from buf[t&1]}. Writes of t+1 overlap compute of t.
__global__ __launch_bounds__(256, 2) void attn_kern(
    const unsigned short* __restrict__ qT, const unsigned short* __restrict__ kT,
    const unsigned short* __restrict__ vK, unsigned short* __restrict__ o_t) {
    __shared__ unsigned short k_t[2 * 64 * 72];   // [buf][j][dd]
    __shared__ unsigned short v_s[2 * 64 * 72];   // [buf][dd][j]
    __shared__ unsigned short p_s[4 * 32 * 72];   // per-wave [i][j]
    int t = threadIdx.x, w = t >> 6, l = t & 63, lr = l & 15, lg = (l >> 4) & 3;
    // XCD-chunked swizzle: 64 consecutive decoded blocks (1 bh) per XCD
    int id = blockIdx.x;
    int lin = (id & 7) * 64 + (id >> 3);
    int qt = lin & 7, bh = lin >> 3;
    int b = bh >> 3, h = bh & 7;
    const unsigned short* qb = qT + (size_t)bh * 1024 * 64;
    const unsigned short* kb = kT + (size_t)bh * 1024 * 64;
    const unsigned short* vb = vK + (size_t)bh * 64 * 1024;
    int i0 = qt * 128 + w * 32;

    // Q fragments: A[row=i][k=dd], rows i0 + it*16 + lr  (b128 loads)
    bf16x8 aq[2][2];
    #pragma unroll
    for (int it = 0; it < 2; ++it)
        #pragma unroll
        for (int kt = 0; kt < 2; ++kt)
            aq[it][kt] = *(const bf16x8*)&qb[(size_t)(i0 + it * 16 + lr) * 64 + kt * 32 + lg * 8];

    bf16x8 ones;
    #pragma unroll
    for (int e = 0; e < 8; ++e) ones[e] = (short)0x3F80;   // bf16 1.0

    float m8[2][4];
    #pragma unroll
    for (int it = 0; it < 2; ++it)
        #pragma unroll
        for (int r = 0; r < 4; ++r) m8[it][r] = -3.0e38f;
    f32x4 accO[2][4] = {};
    f32x4 accL[2] = {};
    unsigned short* pw = p_s + w * (32 * 72);

    // staging: thread t stages 32B of K and 32B of V per tile
    int srow = t >> 2, scol = (t & 3) * 16;
    const unsigned short* kg = kb + srow * 64 + scol;            // K row j=srow
    const unsigned short* vg = vb + (size_t)srow * 1024 + scol;  // V row dd=srow
    int soff = srow * 72 + scol;

    // prologue: tile 0 -> buf0 directly; tile 1 -> regs
    {
        bf16x8 a0 = *(const bf16x8*)kg, a1 = *(const bf16x8*)(kg + 8);
        bf16x8 c0 = *(const bf16x8*)vg, c1 = *(const bf16x8*)(vg + 8);
        *(bf16x8*)&k_t[soff] = a0; *(bf16x8*)&k_t[soff + 8] = a1;
        *(bf16x8*)&v_s[soff] = c0; *(bf16x8*)&v_s[soff + 8] = c1;
    }
    bf16x8 nk0 = *(const bf16x8*)(kg + 4096), nk1 = *(const bf16x8*)(kg + 4096 + 8);
    bf16x8 nv0 = *(const bf16x8*)(vg + 64),   nv1 = *(const bf16x8*)(vg + 64 + 8);

    for (int tile = 0; tile < 16; ++tile) {
        __syncthreads();                       // buf[tile&1] ready; buf[(tile+1)&1] free
        const unsigned short* kc = k_t + (tile & 1) * 4608;
        const unsigned short* vc = v_s + (tile & 1) * 4608;
        if (tile < 15) {
            unsigned short* kn = k_t + ((tile + 1) & 1) * 4608 + soff;
            unsigned short* vn = v_s + ((tile + 1) & 1) * 4608 + soff;
            *(bf16x8*)kn = nk0; *(bf16x8*)(kn + 8) = nk1;
            *(bf16x8*)vn = nv0; *(bf16x8*)(vn + 8) = nv1;
            if (tile < 14) {                   // prefetch tile+2 (hides under compute)
                const unsigned short* kp = kg + (tile + 2) * 4096;
                const unsigned short* vp = vg + (tile + 2) * 64;
                nk0 = *(const bf16x8*)kp; nk1 = *(const bf16x8*)(kp + 8);
                nv0 = *(const bf16x8*)vp; nv1 = *(const bf16x8*)(vp + 8);
            }
        }

        // S = Q K^T  (log2 domain) — bk shared by both i-tiles
        f32x4 s[2][4] = {};
        #pragma unroll
        for (int kt = 0; kt < 2; ++kt) {
            bf16x8 bk[4];
            #pragma unroll
            for (int jt = 0; jt < 4; ++jt)
                bk[jt] = *(const bf16x8*)&kc[(jt * 16 + lr) * 72 + kt * 32 + lg * 8];
            #pragma unroll
            for (int it = 0; it < 2; ++it)
                #pragma unroll
                for (int jt = 0; jt < 4; ++jt)
                    s[it][jt] = MFMA16(aq[it][kt], bk[jt], s[it][jt]);
        }

        // per-row tile max via DPP; defer-max: rescale only on growth
        float sm[2][4];
        float g = -3.0e38f;
        #pragma unroll
        for (int it = 0; it < 2; ++it)
            #pragma unroll
            for (int r = 0; r < 4; ++r) {
                float v0 = fmaxf(fmaxf(s[it][0][r], s[it][1][r]),
                                 fmaxf(s[it][2][r], s[it][3][r]));
                v0 = fmaxf(v0, ROR16(v0, 1));
                v0 = fmaxf(v0, ROR16(v0, 2));
                v0 = fmaxf(v0, ROR16(v0, 4));
                v0 = fmaxf(v0, ROR16(v0, 8));
                sm[it][r] = v0;
                g = fmaxf(g, v0 - m8[it][r]);
            }
        if (__any(g > 11.0f)) {
            #pragma unroll
            for (int it = 0; it < 2; ++it)
                #pragma unroll
                for (int r = 0; r < 4; ++r) {
                    float mn = fmaxf(m8[it][r], sm[it][r]);
                    float al = EXP2(m8[it][r] - mn);
                    accL[it][r] *= al;
                    #pragma unroll
                    for (int dt = 0; dt < 4; ++dt) accO[it][dt][r] *= al;
                    m8[it][r] = mn;
                }
        }

        // P = exp2(S - m), pack to bf16 in wave-private LDS
        #pragma unroll
        for (int it = 0; it < 2; ++it)
            #pragma unroll
            for (int jt = 0; jt < 4; ++jt) {
                unsigned u01 = pk2(EXP2(s[it][jt][0] - m8[it][0]),
                                   EXP2(s[it][jt][1] - m8[it][1]));
                unsigned u23 = pk2(EXP2(s[it][jt][2] - m8[it][2]),
                                   EXP2(s[it][jt][3] - m8[it][3]));
                int row = it * 16 + lg * 4;
                int col = jt * 16 + lr;
                pw[(row + 0) * 72 + col] = (unsigned short)u01;
                pw[(row + 1) * 72 + col] = (unsigned short)(u01 >> 16);
                pw[(row + 2) * 72 + col] = (unsigned short)u23;
                pw[(row + 3) * 72 + col] = (unsigned short)(u23 >> 16);
            }

        // O += P V^T ; L += P * 1  — bv shared by both i-tiles
        #pragma unroll
        for (int kj = 0; kj < 2; ++kj) {
            bf16x8 bv[4];
            #pragma unroll
            for (int dt = 0; dt < 4; ++dt)
                bv[dt] = *(const bf16x8*)&vc[(dt * 16 + lr) * 72 + kj * 32 + lg * 8];
            #pragma unroll
            for (int it = 0; it < 2; ++it) {
                bf16x8 pa = *(const bf16x8*)&pw[(it * 16 + lr) * 72 + kj * 32 + lg * 8];
                accL[it] = MFMA16(pa, ones, accL[it]);
                #pragma unroll
                for (int dt = 0; dt < 4; ++dt)
                    accO[it][dt] = MFMA16(pa, bv[dt], accO[it][dt]);
            }
        }
    }

    // epilogue: o_t[b][i][h*64+dd] = O[i][dd] / l
    #pragma unroll
    for (int it = 0; it < 2; ++it) {
        float inv[4];
        #pragma unroll
        for (int r = 0; r < 4; ++r) inv[r] = 1.0f / accL[it][r];
        #pragma unroll
        for (int dt = 0; dt < 4; ++dt)
            #pragma unroll
            for (int r = 0; r < 4; ++r) {
                int i = i0 + it * 16 + lg * 4 + r;
                o_t[((size_t)b * 1024 + i) * 512 + h * 64 + dt * 16 + lr] =
                    f2bf(accO[it][dt][r] * inv[r]);
            }
    }
}

// ---------------- K5: proj GEMM + bias + residual(xn) -----------------------
__global__ __launch_bounds__(256) void proj_gemm(
    const unsigned short* __restrict__ W, const unsigned short* __restrict__ o_t,
    const float* __restrict__ b_out, const float* __restrict__ x,
    const float* __restrict__ gamma, const float* __restrict__ beta,
    const float2* __restrict__ stats, float* __restrict__ out) {
    __shared__ unsigned short a_t[128 * 72];
    __shared__ unsigned short b_t[128 * 72];
    int t = threadIdx.x, w = t >> 6, l = t & 63, lr = l & 15, lg = l >> 4;
    int jt = blockIdx.x, mt = blockIdx.y, b = blockIdx.z;
    int o0 = mt * 128, j0 = jt * 128;
    int wr = w >> 1, wc = w & 1;
    const unsigned short* Bsrc = o_t + (size_t)b * 1024 * 512;
    f32x4 acc[4][4] = {};
    int srow = t >> 1, sseg = (t & 1) * 32;
    for (int kk = 0; kk < 512; kk += 64) {
        const unsigned short* ga = W    + (size_t)(o0 + srow) * 512 + kk + sseg;
        const unsigned short* gb = Bsrc + (size_t)(j0 + srow) * 512 + kk + sseg;
        bf16x8 a0 = *(const bf16x8*)ga,        a1 = *(const bf16x8*)(ga + 8);
        bf16x8 a2 = *(const bf16x8*)(ga + 16), a3 = *(const bf16x8*)(ga + 24);
        bf16x8 c0 = *(const bf16x8*)gb,        c1 = *(const bf16x8*)(gb + 8);
        bf16x8 c2 = *(const bf16x8*)(gb + 16), c3 = *(const bf16x8*)(gb + 24);
        *(bf16x8*)&a_t[srow * 72 + sseg]      = a0;
        *(bf16x8*)&a_t[srow * 72 + sseg + 8]  = a1;
        *(bf16x8*)&a_t[srow * 72 + sseg + 16] = a2;
        *(bf16x8*)&a_t[srow * 72 + sseg + 24] = a3;
        *(bf16x8*)&b_t[srow * 72 + sseg]      = c0;
        *(bf16x8*)&b_t[srow * 72 + sseg + 8]  = c1;
        *(bf16x8*)&b_t[srow * 72 + sseg + 16] = c2;
        *(bf16x8*)&b_t[srow * 72 + sseg + 24] = c3;
        __syncthreads();
        #pragma unroll
        for (int ks = 0; ks < 2; ++ks) {
            bf16x8 af[4], bfr[4];
            #pragma unroll
            for (int m = 0; m < 4; ++m)
                af[m] = *(const bf16x8*)&a_t[(wr * 64 + m * 16 + lr) * 72 + ks * 32 + lg * 8];
            #pragma unroll
            for (int n = 0; n < 4; ++n)
                bfr[n] = *(const bf16x8*)&b_t[(wc * 64 + n * 16 + lr) * 72 + ks * 32 + lg * 8];
            #pragma unroll
            for (int m = 0; m < 4; ++m)
                #pragma unroll
                for (int n = 0; n < 4; ++n)
                    acc[m][n] = MFMA16(af[m], bfr[n], acc[m][n]);
        }
        __syncthreads();
    }
    #pragma unroll
    for (int m = 0; m < 4; ++m)
        #pragma unroll
        for (int r = 0; r < 4; ++r) {
            int o = o0 + wr * 64 + m * 16 + lg * 4 + r;
            float2 ms = stats[b * 8 + (o >> 6)];
            float g  = gamma[o] * ms.y;
            float bb = beta[o] - ms.x * g + b_out[o];
            const float* xr = x + ((size_t)b * 512 + o) * 1024;
            #pragma unroll
            for (int n = 0; n < 4; ++n) {
                int j = j0 + wc * 64 + n * 16 + lr;
                float xn = fmaf(xr[j], g, bb);
                out[((size_t)b * 512 + o) * 1024 + j] = acc[m][n][r] + xn;
            }
        }
}

// ---------------------------------------------------------------------------
extern "C" void kernel_launch(void* const* d_in, const int* in_sizes, int n_in,
                              void* d_out, int out_size, void* d_ws, size_t ws_size,
                              hipStream_t stream) {
    const float* x     = (const float*)d_in[0];
    const float* gamma = (const float*)d_in[1];
    const float* beta  = (const float*)d_in[2];
    const float* w_qkv = (const float*)d_in[3];
    const float* w_out = (const float*)d_in[4];
    const float* b_out = (const float*)d_in[5];
    float* out = (float*)d_out;

    char* ws = (char*)d_ws;
    unsigned short* wqb   = (unsigned short*)(ws);                    // 1.5 MB
    unsigned short* wob   = (unsigned short*)(ws + 0x180000);         // 0.5 MB
    float2*         stats = (float2*)(ws + 0x200000);                 // 512 B
    unsigned short* xnT   = (unsigned short*)(ws + 0x210000);         // 8 MB
    unsigned short* qT    = (unsigned short*)(ws + 0xA10000);         // 8 MB
    unsigned short* kT    = (unsigned short*)(ws + 0x1210000);        // 8 MB
    unsigned short* vK    = (unsigned short*)(ws + 0x1A10000);        // 8 MB
    unsigned short* o_t   = (unsigned short*)(ws + 0x2210000);        // 8 MB
    // total ~44.1 MB

    cvt_weights<<<768, 256, 0, stream>>>(w_qkv, w_out, wqb, wob);
    gn_stats<<<64, 256, 0, stream>>>(x, stats);
    gn_norm_t<<<dim3(16, 8, 8), 256, 0, stream>>>(x, gamma, beta, stats, xnT);
    qkv_gemm<<<dim3(8, 12, 8), 256, 0, stream>>>(wqb, xnT, qT, kT, vK);
    attn_kern<<<512, 256, 0, stream>>>(qT, kT, vK, o_t);
    proj_gemm<<<dim3(8, 4, 8), 256, 0, stream>>>(wob, o_t, b_out, x, gamma, beta, stats, out);
}